// Round 6
// baseline (295.157 us; speedup 1.0000x reference)
//
#include <hip/hip_runtime.h>

#define NFFT 16000   // 128 * 125
#define BATCH 128
#define DIM 2048
#define TP 17        // padded LDS row stride in K3

__device__ __forceinline__ float2 cmul(float2 a, float2 b) {
    return make_float2(a.x * b.x - a.y * b.y, a.x * b.y + a.y * b.x);
}
__device__ __forceinline__ float2 cadd(float2 a, float2 b) { return make_float2(a.x + b.x, a.y + b.y); }
__device__ __forceinline__ float2 csub(float2 a, float2 b) { return make_float2(a.x - b.x, a.y - b.y); }
__device__ __forceinline__ float2 cis(float ang) { return make_float2(__cosf(ang), __sinf(ang)); }

__device__ __forceinline__ int rev5_3(int n) {
    int d0 = n % 5, r = n / 5;
    int d1 = r % 5, d2 = r / 5;
    return d0 * 25 + d1 * 5 + d2;
}
__device__ __forceinline__ int rev7(int x) { return (int)(__brev((unsigned)x) >> 25); }

__device__ __forceinline__ float2 shfl2(float2 v, int lane) {
    return make_float2(__shfl(v.x, lane), __shfl(v.y, lane));
}
__device__ __forceinline__ float2 shfl2_xor(float2 v, int mask) {
    return make_float2(__shfl_xor(v.x, mask), __shfl_xor(v.y, mask));
}

// packed-spectrum pointwise: conj(G)[k] given Zk=Z[k], Zm=Z[N-k]
__device__ __forceinline__ float2 conjG(float2 Zk, float2 Zm) {
    float u = (Zk.x * Zk.x - Zk.y * Zk.y) - (Zm.x * Zm.x - Zm.y * Zm.y);
    float v = 2.f * (Zk.x * Zk.y + Zm.x * Zm.y);
    return make_float2(0.25f * v, 0.25f * u);
}

// in-register 128-point DIF FFT across one wave; twiddles hoisted (lane-only).
// lane l holds positions l (x0), l+64 (x1); output: x0=X[rev7(l)], x1=X[rev7(l)+1]
__device__ __forceinline__ void dif128(float2& x0, float2& x1, const float2* tw, int l) {
    {   // stage m=64 (register-local)
        float2 a = x0, b = x1;
        x0 = cadd(a, b);
        x1 = cmul(csub(a, b), tw[0]);
    }
    int s = 1;
    #pragma unroll
    for (int m = 32; m >= 1; m >>= 1, ++s) {
        float2 w = tw[s];
        float2 o0 = shfl2_xor(x0, m), o1 = shfl2_xor(x1, m);
        if (l & m) {
            x0 = cmul(csub(o0, x0), w);
            x1 = cmul(csub(o1, x1), w);
        } else {
            x0 = cadd(x0, o0);
            x1 = cadd(x1, o1);
        }
    }
}

// ---- find the single nonzero (idx, sign) in each row of C1/C2 ----
__global__ void extract_sketch(const float* __restrict__ C1, const float* __restrict__ C2,
                               int* __restrict__ idx1, float* __restrict__ sgn1,
                               int* __restrict__ idx2, float* __restrict__ sgn2) {
    int gwave = (blockIdx.x * blockDim.x + threadIdx.x) >> 6;
    int lane = threadIdx.x & 63;
    if (gwave >= 2 * DIM) return;
    const float* row;
    int* idxp; float* sgnp; int d;
    if (gwave < DIM) { d = gwave;       row = C1 + (size_t)d * NFFT; idxp = idx1; sgnp = sgn1; }
    else             { d = gwave - DIM; row = C2 + (size_t)d * NFFT; idxp = idx2; sgnp = sgn2; }
    for (int step = 0; step < 16; ++step) {
        int off0 = step * 1024 + lane * 4;
        float4 v[4];
        #pragma unroll
        for (int c = 0; c < 4; ++c) {
            int off = off0 + c * 256;
            v[c] = (off < NFFT) ? *reinterpret_cast<const float4*>(row + off)
                                : make_float4(0.f, 0.f, 0.f, 0.f);
        }
        bool found = false;
        #pragma unroll
        for (int c = 0; c < 4; ++c) {
            float4 w = v[c];
            if (w.x != 0.f || w.y != 0.f || w.z != 0.f || w.w != 0.f) {
                int off = off0 + c * 256;
                int j; float s;
                if (w.x != 0.f)      { j = 0; s = w.x; }
                else if (w.y != 0.f) { j = 1; s = w.y; }
                else if (w.z != 0.f) { j = 2; s = w.z; }
                else                 { j = 3; s = w.w; }
                idxp[d] = off + j;
                sgnp[d] = s;
                found = true;
            }
        }
        if (__any(found)) return;
    }
}

// ---- K1: scatter + 125-point column FFTs (over n2) + inter-dim twiddle ----
// grid = 128 b x 4 quarters, 512 threads; writes U[b][k2*128 + n1] = S[n1][k2]*W_N^{n1*k2}
__global__ void __launch_bounds__(512) k1_colfft(
        const float* __restrict__ x1, const float* __restrict__ x2,
        const int* __restrict__ idx1, const float* __restrict__ sgn1,
        const int* __restrict__ idx2, const float* __restrict__ sgn2,
        float2* __restrict__ U) {
    __shared__ float2 S[32 * 125];
    const int b = blockIdx.x >> 2, q = blockIdx.x & 3;
    const int tid = threadIdx.x;

    for (int i = tid; i < 32 * 125; i += 512) S[i] = make_float2(0.f, 0.f);
    __syncthreads();

    const float* x1b = x1 + (size_t)b * DIM;
    const float* x2b = x2 + (size_t)b * DIM;
    for (int d = tid; d < DIM; d += 512) {
        int p1 = idx1[d]; int n1a = p1 & 127;
        if ((n1a >> 5) == q) atomicAdd(&S[(n1a & 31) * 125 + rev5_3(p1 >> 7)].x, sgn1[d] * x1b[d]);
        int p2 = idx2[d]; int n1b = p2 & 127;
        if ((n1b >> 5) == q) atomicAdd(&S[(n1b & 31) * 125 + rev5_3(p2 >> 7)].y, sgn2[d] * x2b[d]);
    }
    __syncthreads();

    const float C1_5 = 0.30901699437494742f, S1_5 = 0.95105651629515357f;
    const float C2_5 = -0.80901699437494745f, S2_5 = 0.58778525229247312f;
    const float2 w5tab[5] = { make_float2(1.f, 0.f),
                              make_float2(C1_5, -S1_5), make_float2(C2_5, -S2_5),
                              make_float2(C2_5,  S2_5), make_float2(C1_5,  S1_5) };
    #pragma unroll
    for (int s = 0; s < 3; ++s) {
        const int m = (s == 0) ? 1 : (s == 1) ? 5 : 25;
        const float angstep = -6.28318530717958647692f / (float)(5 * m);
        for (int task = tid; task < 32 * 25; task += 512) {
            int row = task / 25;
            int bf = task - row * 25;
            int t = bf % m, blk = bf / m;
            int base = row * 125 + blk * (5 * m) + t;
            float2 xv[5];
            #pragma unroll
            for (int r = 0; r < 5; ++r) xv[r] = S[base + r * m];
            if (m > 1) {
                float2 w1 = cis(angstep * (float)t);
                float2 w2 = cmul(w1, w1), w3 = cmul(w2, w1), w4 = cmul(w2, w2);
                xv[1] = cmul(xv[1], w1); xv[2] = cmul(xv[2], w2);
                xv[3] = cmul(xv[3], w3); xv[4] = cmul(xv[4], w4);
            }
            float2 y[5];
            #pragma unroll
            for (int qq = 0; qq < 5; ++qq) {
                float2 acc = xv[0];
                #pragma unroll
                for (int r = 1; r < 5; ++r) {
                    float2 t2 = cmul(xv[r], w5tab[(qq * r) % 5]);
                    acc.x += t2.x; acc.y += t2.y;
                }
                y[qq] = acc;
            }
            #pragma unroll
            for (int qq = 0; qq < 5; ++qq) S[base + qq * m] = y[qq];
        }
        __syncthreads();
    }

    const float ANGN = -6.28318530717958647692f / 16000.0f;
    const int n1base = q * 32;
    float2* Ub = U + (size_t)b * NFFT;
    for (int i = tid; i < 32 * 125; i += 512) {
        int n1l = i & 31, k2 = i >> 5;
        int n1 = n1base + n1l;
        Ub[k2 * 128 + n1] = cmul(S[n1l * 125 + k2], cis(ANGN * (float)(n1 * k2)));
    }
}

// ---- K2: per-wave column-pair, zero-LDS zero-barrier ----
// V-symmetry: V_{125-c}[j1] = conj(V_c[j1]), so only columns 0..62 are computed
// through the inverse-start FFT and stored. (Second column's forward FFT is still
// needed for the pointwise partner exchange.)
__global__ void __launch_bounds__(256) k2_pair(const float2* __restrict__ U,
                                               float2* __restrict__ V) {
    const int w = threadIdx.x >> 6, l = threadIdx.x & 63;
    const int task = blockIdx.x * 4 + w;          // 2016*4 = 8064 = 128*63 exactly
    const int b = task / 63, cg = task - b * 63;
    const int c = cg, cm = cg ? 125 - cg : 0;
    const float2* Ub = U + (size_t)b * NFFT;
    const float PI_F = 3.14159265358979323846f;

    // hoisted dif128 twiddles (lane-only), reused across all FFT calls
    float2 tw[7];
    tw[0] = cis(-PI_F / 64.0f * (float)l);
    {
        int m = 32;
        #pragma unroll
        for (int s = 1; s < 7; ++s, m >>= 1)
            tw[s] = cis(-PI_F / (float)m * (float)(l & (m - 1)));
    }

    float2 a0 = Ub[c * 128 + l], a1 = Ub[c * 128 + l + 64];
    dif128(a0, a1, tw, l);
    float2 b0, b1;
    if (cg) {
        b0 = Ub[cm * 128 + l]; b1 = Ub[cm * 128 + l + 64];
        dif128(b0, b1, tw, l);
    }

    const int e  = rev7(l);           // even; lane holds rows e, e+1
    const int lp = rev7(126 - e);     // holder lane of rows 126-e (reg0) / 127-e (reg1)

    // pointwise for column c only (partner rows from column cm via shfl)
    float2 gA0, gA1;
    if (cg) {
        float2 zm0 = shfl2(b1, lp);   // Zcm[127-e]
        float2 zm1 = shfl2(b0, lp);   // Zcm[126-e]
        gA0 = conjG(a0, zm0);         // G'_c[e]
        gA1 = conjG(a1, zm1);         // G'_c[e+1]
    } else {
        int hz = rev7((128 - e) & 127);
        float2 zm0 = shfl2(a0, hz);   // Z0[(128-e)&127]
        float2 zm1 = shfl2(a1, lp);   // Z0[127-e]
        gA0 = conjG(a0, zm0);
        gA1 = conjG(a1, zm1);
    }

    // re-permute bit-reversed G' back to natural order for the inverse-start FFT:
    // G'[l] / G'[l+64] live as reg (l&1 ? 1 : 0) of lane q / q+1, q = rev7(l&~1)
    const int q = rev7(l & 62);
    const float ANGN = -6.28318530717958647692f / 16000.0f;
    float2* Vb = V + (size_t)b * NFFT;

    float2 t00 = shfl2(gA0, q),     t10 = shfl2(gA1, q);
    float2 t01 = shfl2(gA0, q + 1), t11 = shfl2(gA1, q + 1);
    float2 p0 = (l & 1) ? t10 : t00;
    float2 p1 = (l & 1) ? t11 : t01;
    dif128(p0, p1, tw, l);
    p0 = cmul(p0, cis(ANGN * (float)(c * e)));
    p1 = cmul(p1, cis(ANGN * (float)(c * (e + 1))));
    *reinterpret_cast<float4*>(&Vb[c * 128 + e]) = make_float4(p0.x, p0.y, p1.x, p1.y);
}

// ---- K3: 125-point row FFTs (over m1) per (b, 16-wide j1 tile); real output ----
// columns m1 in [63,124] synthesized as conj(V[125-m1]) (V-symmetry)
__global__ void __launch_bounds__(256) k3_rowfft(const float2* __restrict__ V,
                                                 float* __restrict__ out) {
    __shared__ float2 T[125 * TP];
    const int b = blockIdx.x >> 3, g = blockIdx.x & 7;
    const int j1base = g * 16, tid = threadIdx.x;
    const float2* Vb = V + (size_t)b * NFFT;

    for (int i = tid; i < 125 * 16; i += 256) {
        int m1 = i >> 4, j1l = i & 15;
        float2 v;
        if (m1 <= 62) {
            v = Vb[m1 * 128 + j1base + j1l];
        } else {
            v = Vb[(125 - m1) * 128 + j1base + j1l];
            v.y = -v.y;
        }
        T[rev5_3(m1) * TP + j1l] = v;
    }
    __syncthreads();

    const float C1_5 = 0.30901699437494742f, S1_5 = 0.95105651629515357f;
    const float C2_5 = -0.80901699437494745f, S2_5 = 0.58778525229247312f;
    const float2 w5tab[5] = { make_float2(1.f, 0.f),
                              make_float2(C1_5, -S1_5), make_float2(C2_5, -S2_5),
                              make_float2(C2_5,  S2_5), make_float2(C1_5,  S1_5) };
    #pragma unroll
    for (int s = 0; s < 3; ++s) {
        const int m = (s == 0) ? 1 : (s == 1) ? 5 : 25;
        const float angstep = -6.28318530717958647692f / (float)(5 * m);
        for (int task = tid; task < 16 * 25; task += 256) {
            int bf = task >> 4;
            int j1l = task & 15;
            int t = bf % m, blk = bf / m;
            int base = (blk * (5 * m) + t) * TP + j1l;
            float2 xv[5];
            #pragma unroll
            for (int r = 0; r < 5; ++r) xv[r] = T[base + r * m * TP];
            if (m > 1) {
                float2 w1 = cis(angstep * (float)t);
                float2 w2 = cmul(w1, w1), w3 = cmul(w2, w1), w4 = cmul(w2, w2);
                xv[1] = cmul(xv[1], w1); xv[2] = cmul(xv[2], w2);
                xv[3] = cmul(xv[3], w3); xv[4] = cmul(xv[4], w4);
            }
            float2 y[5];
            #pragma unroll
            for (int qq = 0; qq < 5; ++qq) {
                float2 acc = xv[0];
                #pragma unroll
                for (int r = 1; r < 5; ++r) {
                    float2 t2 = cmul(xv[r], w5tab[(qq * r) % 5]);
                    acc.x += t2.x; acc.y += t2.y;
                }
                y[qq] = acc;
            }
            #pragma unroll
            for (int qq = 0; qq < 5; ++qq) T[base + qq * m * TP] = y[qq];
        }
        __syncthreads();
    }

    const float invN = 1.0f / (float)NFFT;
    float* outb = out + (size_t)b * NFFT;
    for (int i = tid; i < 125 * 16; i += 256) {
        int j2 = i >> 4, j1l = i & 15;
        outb[j1base + j1l + 128 * j2] = T[j2 * TP + j1l].x * invN;
    }
}

extern "C" void kernel_launch(void* const* d_in, const int* in_sizes, int n_in,
                              void* d_out, int out_size, void* d_ws, size_t ws_size,
                              hipStream_t stream) {
    (void)in_sizes; (void)n_in; (void)out_size; (void)ws_size;
    const float* x1 = (const float*)d_in[0];
    const float* x2 = (const float*)d_in[1];
    const float* C1 = (const float*)d_in[2];
    const float* C2 = (const float*)d_in[3];
    float* out = (float*)d_out;

    char* w = (char*)d_ws;
    int*    idx1 = (int*)  (w);                       // 8 KB
    float*  sgn1 = (float*)(w + 8192);                // 8 KB
    int*    idx2 = (int*)  (w + 16384);               // 8 KB
    float*  sgn2 = (float*)(w + 24576);               // 8 KB
    float2* U    = (float2*)(w + 32768);              // 16.384 MB
    float2* V    = (float2*)(w + 32768 + 16384000);   // columns 0..62 live

    extract_sketch<<<(2 * DIM) / 4, 256, 0, stream>>>(C1, C2, idx1, sgn1, idx2, sgn2);
    k1_colfft     <<<BATCH * 4, 512, 0, stream>>>(x1, x2, idx1, sgn1, idx2, sgn2, U);
    k2_pair       <<<2016, 256, 0, stream>>>(U, V);
    k3_rowfft     <<<BATCH * 8, 256, 0, stream>>>(V, out);
}